// Round 2
// baseline (1625.891 us; speedup 1.0000x reference)
//
#include <hip/hip_runtime.h>
#include <hip/hip_bf16.h>
#include <math.h>

// Shapes are fixed by the problem instance.
#define BDOCS   1024
#define CNODES  4096
#define INDIM   768
#define HID     512
#define NHEAD   4
#define HDIM    128
#define NEG_SLOPE 0.2f

__device__ __forceinline__ float lrelu(float x) { return x > 0.f ? x : NEG_SLOPE * x; }

// ---------------------------------------------------------------------------
// Tiled GEMM: C[M,N] = A[M,K] @ B[K,N]  (or A @ B^T when BT, B is [N,K])
// 64x64 tile, 256 threads, 4x4 microtile, fp32 accumulate.
// ELUA: apply elu() to A elements on load. BIASRELU: epilogue relu(x + bias).
// ---------------------------------------------------------------------------
template <bool BT, bool ELUA, bool BIASRELU>
__global__ __launch_bounds__(256)
void gemm64(const float* __restrict__ A, const float* __restrict__ B,
            const float* __restrict__ bias,
            float* __restrict__ Cmat, int M, int N, int K)
{
    __shared__ __align__(16) float As[16][68];   // [kk][m], 68*4B row stride = 17*16B
    __shared__ __align__(16) float Bs[16][68];   // [kk][n]

    const int t  = threadIdx.x;
    const int m0 = blockIdx.y * 64;
    const int n0 = blockIdx.x * 64;
    const int ty = t >> 4, tx = t & 15;

    float acc[4][4] = {};

    const int am  = t >> 2;          // 0..63
    const int ak0 = (t & 3) * 4;     // 0,4,8,12

    for (int k0 = 0; k0 < K; k0 += 16) {
        // stage A tile: As[kk][m] = A[m0+m][k0+kk]
        {
            const float* ap = A + (size_t)(m0 + am) * K + k0 + ak0;
#pragma unroll
            for (int q = 0; q < 4; q++) {
                float v = ap[q];
                if (ELUA) v = v > 0.f ? v : (__expf(v) - 1.f);
                As[ak0 + q][am] = v;
            }
        }
        // stage B tile
        if (!BT) {
            const int kr = t >> 4, c = (t & 15) * 4;
            const float* bp = B + (size_t)(k0 + kr) * N + n0 + c;
#pragma unroll
            for (int q = 0; q < 4; q++) Bs[kr][c + q] = bp[q];
        } else {
            const int n = t >> 2, kk0 = (t & 3) * 4;
            const float* bp = B + (size_t)(n0 + n) * K + k0 + kk0;
#pragma unroll
            for (int q = 0; q < 4; q++) Bs[kk0 + q][n] = bp[q];
        }
        __syncthreads();

#pragma unroll
        for (int kk = 0; kk < 16; kk++) {
            float4 a4 = *(const float4*)&As[kk][ty * 4];
            float4 b4 = *(const float4*)&Bs[kk][tx * 4];
            float av[4] = {a4.x, a4.y, a4.z, a4.w};
            float bv[4] = {b4.x, b4.y, b4.z, b4.w};
#pragma unroll
            for (int i2 = 0; i2 < 4; i2++)
#pragma unroll
                for (int j2 = 0; j2 < 4; j2++)
                    acc[i2][j2] += av[i2] * bv[j2];
        }
        __syncthreads();
    }

#pragma unroll
    for (int i2 = 0; i2 < 4; i2++) {
        const int m = m0 + ty * 4 + i2;
#pragma unroll
        for (int j2 = 0; j2 < 4; j2++) {
            const int n = n0 + tx * 4 + j2;
            float v = acc[i2][j2];
            if (BIASRELU) { v += bias[n]; v = fmaxf(v, 0.f); }
            Cmat[(size_t)m * N + n] = v;
        }
    }
}

// ---------------------------------------------------------------------------
// asrc[h,i] = sum_d hpre[i, h*128+d] * a_src[h,d]   (same for adst)
// hpre fp32 (C x 512). One block (512 thr) per node i.
// ---------------------------------------------------------------------------
__global__ __launch_bounds__(512)
void attn_prep(const float* __restrict__ hpre,
               const float* __restrict__ a_src,
               const float* __restrict__ a_dst,
               float* __restrict__ asrc, float* __restrict__ adst)
{
    const int i = blockIdx.x;
    const int t = threadIdx.x;  // 512 = H*D, flat index h*128+d matches a_src layout
    __shared__ float s1[512], s2[512];
    const float hv = hpre[(size_t)i * HID + t];
    s1[t] = hv * a_src[t];
    s2[t] = hv * a_dst[t];
    __syncthreads();
    for (int s = 64; s >= 1; s >>= 1) {
        if ((t & 127) < s) { s1[t] += s1[t + s]; s2[t] += s2[t + s]; }
        __syncthreads();
    }
    if ((t & 127) == 0) {
        const int h = t >> 7;
        asrc[h * CNODES + i] = s1[t];
        adst[h * CNODES + i] = s2[t];
    }
}

// ---------------------------------------------------------------------------
// Per row i, all heads: m[h,i] = max_{j: adj=1} lrelu(asrc+adst_j)   (monotone
// lrelu => use masked max of adst), then linv = 1/sum exp(e - m).
// ---------------------------------------------------------------------------
__global__ __launch_bounds__(256)
void attn_stats(const int* __restrict__ adj,
                const float* __restrict__ asrc, const float* __restrict__ adst,
                float* __restrict__ mrow, float* __restrict__ linv)
{
    const int i = blockIdx.x;
    const int t = threadIdx.x;  // 256
    __shared__ float red[NHEAD][256];

    float mx[NHEAD];
#pragma unroll
    for (int h = 0; h < NHEAD; h++) mx[h] = -1e30f;
    for (int j = t; j < CNODES; j += 256) {
        if (adj[(size_t)i * CNODES + j]) {
#pragma unroll
            for (int h = 0; h < NHEAD; h++) mx[h] = fmaxf(mx[h], adst[h * CNODES + j]);
        }
    }
#pragma unroll
    for (int h = 0; h < NHEAD; h++) red[h][t] = mx[h];
    __syncthreads();
    for (int s = 128; s >= 1; s >>= 1) {
        if (t < s) {
#pragma unroll
            for (int h = 0; h < NHEAD; h++) red[h][t] = fmaxf(red[h][t], red[h][t + s]);
        }
        __syncthreads();
    }
    float as[NHEAD], m[NHEAD];
#pragma unroll
    for (int h = 0; h < NHEAD; h++) {
        as[h] = asrc[h * CNODES + i];
        m[h]  = lrelu(as[h] + red[h][0]);
    }
    __syncthreads();

    float sm[NHEAD] = {};
    for (int j = t; j < CNODES; j += 256) {
        if (adj[(size_t)i * CNODES + j]) {
#pragma unroll
            for (int h = 0; h < NHEAD; h++)
                sm[h] += __expf(lrelu(as[h] + adst[h * CNODES + j]) - m[h]);
        }
    }
#pragma unroll
    for (int h = 0; h < NHEAD; h++) red[h][t] = sm[h];
    __syncthreads();
    for (int s = 128; s >= 1; s >>= 1) {
        if (t < s) {
#pragma unroll
            for (int h = 0; h < NHEAD; h++) red[h][t] += red[h][t + s];
        }
        __syncthreads();
    }
    if (t < NHEAD) {
        mrow[t * CNODES + i] = m[t];
        linv[t * CNODES + i] = 1.0f / red[t][0];
    }
}

// ---------------------------------------------------------------------------
// out[i, h*128+d] = (1/l_i^h) * sum_j w^h_ij * hpre[j, h*128+d]
// Block: 512 threads = (h = t>>7, d = t&127), TI=8 rows per block, CJ=64 cols
// per chunk. w tile computed into LDS (phase A), then FMA sweep (phase B).
// ---------------------------------------------------------------------------
#define TI 8
#define CJ 64
__global__ __launch_bounds__(512)
void attn_out(const float* __restrict__ hpre, const int* __restrict__ adj,
              const float* __restrict__ asrc, const float* __restrict__ adst,
              const float* __restrict__ mrow, const float* __restrict__ linv,
              float* __restrict__ out)
{
    const int i0 = blockIdx.x * TI;
    const int t  = threadIdx.x;       // 512
    const int h  = t >> 7;
    const int d  = t & 127;

    __shared__ __align__(16) float s_w[NHEAD][TI][CJ];      // 8 KB
    __shared__ float s_as[NHEAD][TI], s_m[NHEAD][TI], s_li[NHEAD][TI];

    if (t < NHEAD * TI) {
        const int hh = t >> 3, r = t & 7;
        s_as[hh][r] = asrc[hh * CNODES + i0 + r];
        s_m[hh][r]  = mrow[hh * CNODES + i0 + r];
        s_li[hh][r] = linv[hh * CNODES + i0 + r];
    }
    __syncthreads();

    float acc[TI] = {};
    const int wr = t >> 6;    // 0..7
    const int wj = t & 63;    // 0..63

    for (int j0 = 0; j0 < CNODES; j0 += CJ) {
        // phase A: 4*8*64 = 2048 w values, 4 per thread (head = k)
        const int a = adj[(size_t)(i0 + wr) * CNODES + j0 + wj];
#pragma unroll
        for (int k = 0; k < NHEAD; k++) {
            float w = 0.f;
            if (a) {
                float e = lrelu(s_as[k][wr] + adst[k * CNODES + j0 + wj]);
                w = __expf(e - s_m[k][wr]);
            }
            s_w[k][wr][wj] = w;
        }
        __syncthreads();

        // phase B: acc[r] += w[h][r][jj] * hpre[j0+jj][h*128+d]
        for (int jj4 = 0; jj4 < CJ; jj4 += 4) {
            const float hv0 = hpre[(size_t)(j0 + jj4 + 0) * HID + h * HDIM + d];
            const float hv1 = hpre[(size_t)(j0 + jj4 + 1) * HID + h * HDIM + d];
            const float hv2 = hpre[(size_t)(j0 + jj4 + 2) * HID + h * HDIM + d];
            const float hv3 = hpre[(size_t)(j0 + jj4 + 3) * HID + h * HDIM + d];
#pragma unroll
            for (int r = 0; r < TI; r++) {
                float4 w4 = *(const float4*)&s_w[h][r][jj4];
                acc[r] += w4.x * hv0 + w4.y * hv1 + w4.z * hv2 + w4.w * hv3;
            }
        }
        __syncthreads();
    }

#pragma unroll
    for (int r = 0; r < TI; r++)
        out[(size_t)(i0 + r) * HID + h * HDIM + d] = acc[r] * s_li[h][r];
}

// ---------------------------------------------------------------------------
extern "C" void kernel_launch(void* const* d_in, const int* in_sizes, int n_in,
                              void* d_out, int out_size, void* d_ws, size_t ws_size,
                              hipStream_t stream)
{
    const float* doc_x      = (const float*)d_in[0];
    const float* label_init = (const float*)d_in[1];
    const int*   adj        = (const int*)d_in[2];
    const float* W1         = (const float*)d_in[3];
    const float* a_src1     = (const float*)d_in[4];
    const float* a_dst1     = (const float*)d_in[5];
    const float* W2         = (const float*)d_in[6];
    const float* a_src2     = (const float*)d_in[7];
    const float* a_dst2     = (const float*)d_in[8];
    const float* Wd         = (const float*)d_in[9];
    const float* bd         = (const float*)d_in[10];
    float*       out        = (float*)d_out;

    float* ws    = (float*)d_ws;
    float* doc_h = ws;                          // 1024*512
    float* buf1  = doc_h + (size_t)BDOCS * HID; // 4096*512  (hpre of current layer)
    float* buf2  = buf1 + (size_t)CNODES * HID; // 4096*512  (gat output of current layer)
    float* asrc  = buf2 + (size_t)CNODES * HID; // 4*4096
    float* adst  = asrc + NHEAD * CNODES;
    float* mrow  = adst + NHEAD * CNODES;
    float* linv  = mrow + NHEAD * CNODES;

    const dim3 blk(256);

    // doc_h = relu(doc_x @ Wd + bd)
    gemm64<false, false, true>
        <<<dim3(HID / 64, BDOCS / 64), blk, 0, stream>>>(doc_x, Wd, bd, doc_h, BDOCS, HID, INDIM);

    // hpre1 = label_init @ W1  -> buf1
    gemm64<false, false, false>
        <<<dim3(HID / 64, CNODES / 64), blk, 0, stream>>>(label_init, W1, nullptr, buf1, CNODES, HID, INDIM);

    // GAT layer 1: buf1 -> buf2
    attn_prep<<<CNODES, 512, 0, stream>>>(buf1, a_src1, a_dst1, asrc, adst);
    attn_stats<<<CNODES, 256, 0, stream>>>(adj, asrc, adst, mrow, linv);
    attn_out<<<CNODES / TI, 512, 0, stream>>>(buf1, adj, asrc, adst, mrow, linv, buf2);

    // hpre2 = elu(buf2) @ W2 -> buf1
    gemm64<false, true, false>
        <<<dim3(HID / 64, CNODES / 64), blk, 0, stream>>>(buf2, W2, nullptr, buf1, CNODES, HID, HID);

    // GAT layer 2: buf1 -> buf2 (= label_h)
    attn_prep<<<CNODES, 512, 0, stream>>>(buf1, a_src2, a_dst2, asrc, adst);
    attn_stats<<<CNODES, 256, 0, stream>>>(adj, asrc, adst, mrow, linv);
    attn_out<<<CNODES / TI, 512, 0, stream>>>(buf1, adj, asrc, adst, mrow, linv, buf2);

    // logits = doc_h @ label_h^T -> out
    gemm64<true, false, false>
        <<<dim3(CNODES / 64, BDOCS / 64), blk, 0, stream>>>(doc_h, buf2, nullptr, out, BDOCS, CNODES, HID);
}

// Round 3
// 751.009 us; speedup vs baseline: 2.1649x; 2.1649x over previous
//
#include <hip/hip_runtime.h>
#include <hip/hip_bf16.h>
#include <math.h>

// Shapes are fixed by the problem instance.
#define BDOCS   1024
#define CNODES  4096
#define INDIM   768
#define HID     512
#define NHEAD   4
#define HDIM    128
#define NEG_SLOPE 0.2f

typedef __attribute__((ext_vector_type(8))) short short8;   // 8 bf16 (4 VGPRs)
typedef __attribute__((ext_vector_type(4))) float f32x4;    // MFMA C/D

__device__ __forceinline__ float lrelu(float x) { return x > 0.f ? x : NEG_SLOPE * x; }

// float -> bf16 bits, round-to-nearest-even (no NaN inputs here)
__device__ __forceinline__ short f2bf(float f) {
    union { float f; unsigned u; } v; v.f = f;
    unsigned r = (v.u + 0x7fff + ((v.u >> 16) & 1)) >> 16;
    return (short)r;
}

__device__ __forceinline__ void gl_lds16(const short* g, short* l) {
    __builtin_amdgcn_global_load_lds(
        (const __attribute__((address_space(1))) unsigned int*)g,
        (__attribute__((address_space(3))) unsigned int*)l, 16, 0, 0);
}

// ---------------------------------------------------------------------------
// Tiled GEMM: C[M,N] = A[M,K] @ B[K,N]  (or A @ B^T when BT, B is [N,K])
// 64x64 tile, 256 threads, 4x4 microtile, fp32 accumulate.
// ---------------------------------------------------------------------------
template <bool BT, bool ELUA, bool BIASRELU>
__global__ __launch_bounds__(256)
void gemm64(const float* __restrict__ A, const float* __restrict__ B,
            const float* __restrict__ bias,
            float* __restrict__ Cmat, int M, int N, int K)
{
    __shared__ __align__(16) float As[16][68];
    __shared__ __align__(16) float Bs[16][68];

    const int t  = threadIdx.x;
    const int m0 = blockIdx.y * 64;
    const int n0 = blockIdx.x * 64;
    const int ty = t >> 4, tx = t & 15;

    float acc[4][4] = {};

    const int am  = t >> 2;
    const int ak0 = (t & 3) * 4;

    for (int k0 = 0; k0 < K; k0 += 16) {
        {
            const float* ap = A + (size_t)(m0 + am) * K + k0 + ak0;
#pragma unroll
            for (int q = 0; q < 4; q++) {
                float v = ap[q];
                if (ELUA) v = v > 0.f ? v : (__expf(v) - 1.f);
                As[ak0 + q][am] = v;
            }
        }
        if (!BT) {
            const int kr = t >> 4, c = (t & 15) * 4;
            const float* bp = B + (size_t)(k0 + kr) * N + n0 + c;
#pragma unroll
            for (int q = 0; q < 4; q++) Bs[kr][c + q] = bp[q];
        } else {
            const int n = t >> 2, kk0 = (t & 3) * 4;
            const float* bp = B + (size_t)(n0 + n) * K + k0 + kk0;
#pragma unroll
            for (int q = 0; q < 4; q++) Bs[kk0 + q][n] = bp[q];
        }
        __syncthreads();

#pragma unroll
        for (int kk = 0; kk < 16; kk++) {
            float4 a4 = *(const float4*)&As[kk][ty * 4];
            float4 b4 = *(const float4*)&Bs[kk][tx * 4];
            float av[4] = {a4.x, a4.y, a4.z, a4.w};
            float bv[4] = {b4.x, b4.y, b4.z, b4.w};
#pragma unroll
            for (int i2 = 0; i2 < 4; i2++)
#pragma unroll
                for (int j2 = 0; j2 < 4; j2++)
                    acc[i2][j2] += av[i2] * bv[j2];
        }
        __syncthreads();
    }

#pragma unroll
    for (int i2 = 0; i2 < 4; i2++) {
        const int m = m0 + ty * 4 + i2;
#pragma unroll
        for (int j2 = 0; j2 < 4; j2++) {
            const int n = n0 + tx * 4 + j2;
            float v = acc[i2][j2];
            if (BIASRELU) { v += bias[n]; v = fmaxf(v, 0.f); }
            Cmat[(size_t)m * N + n] = v;
        }
    }
}

// ---------------------------------------------------------------------------
// asrc[h,i] = sum_d hpre[i, h*128+d] * a_src[h,d]   (same for adst)
// ---------------------------------------------------------------------------
__global__ __launch_bounds__(512)
void attn_prep(const float* __restrict__ hpre,
               const float* __restrict__ a_src,
               const float* __restrict__ a_dst,
               float* __restrict__ asrc, float* __restrict__ adst)
{
    const int i = blockIdx.x;
    const int t = threadIdx.x;  // 512 = H*D
    __shared__ float s1[512], s2[512];
    const float hv = hpre[(size_t)i * HID + t];
    s1[t] = hv * a_src[t];
    s2[t] = hv * a_dst[t];
    __syncthreads();
    for (int s = 64; s >= 1; s >>= 1) {
        if ((t & 127) < s) { s1[t] += s1[t + s]; s2[t] += s2[t + s]; }
        __syncthreads();
    }
    if ((t & 127) == 0) {
        const int h = t >> 7;
        asrc[h * CNODES + i] = s1[t];
        adst[h * CNODES + i] = s2[t];
    }
}

// ---------------------------------------------------------------------------
// Mh[h] = max_j adst[h][j]  (global, unmasked — valid upper bound for the
// softmax shift; exact softmax is shift-invariant)
// ---------------------------------------------------------------------------
__global__ __launch_bounds__(256)
void adst_max(const float* __restrict__ adst, float* __restrict__ Mh)
{
    const int h = blockIdx.x, t = threadIdx.x;
    __shared__ float red[256];
    float m = -1e30f;
    for (int j = t; j < CNODES; j += 256) m = fmaxf(m, adst[h * CNODES + j]);
    red[t] = m; __syncthreads();
    for (int s = 128; s >= 1; s >>= 1) {
        if (t < s) red[t] = fmaxf(red[t], red[t + s]);
        __syncthreads();
    }
    if (t == 0) Mh[h] = red[0];
}

// ---------------------------------------------------------------------------
// hbT[n][i] = bf16(hpre[i][n])   (512 x 4096), 64x64 LDS transpose tiles
// ---------------------------------------------------------------------------
__global__ __launch_bounds__(256)
void transpose_cvt(const float* __restrict__ src, __hip_bfloat16* __restrict__ dst)
{
    __shared__ float tile[64][65];
    const int i0 = blockIdx.x * 64;   // 64 blocks
    const int n0 = blockIdx.y * 64;   // 8 blocks
    const int c  = threadIdx.x & 63, r4 = threadIdx.x >> 6;
    for (int rr = r4; rr < 64; rr += 4)
        tile[rr][c] = src[(size_t)(i0 + rr) * HID + n0 + c];
    __syncthreads();
    for (int nn = r4; nn < 64; nn += 4)
        dst[(size_t)(n0 + nn) * CNODES + i0 + c] = __float2bfloat16(tile[c][nn]);
}

// ---------------------------------------------------------------------------
// out[i, h*128+d] = (1/l) * sum_j w_ij * V[j][d]   via bf16 MFMA.
// Block: 256 thr = 4 waves, wave = head. i-tile 16 rows, K-chunk 32.
// P tile written in MFMA A-layout; V staged k-contiguous from hbT via
// global_load_lds(16B). l accumulated in registers, reduced at end.
// ---------------------------------------------------------------------------
__global__ __launch_bounds__(256)
void attn_out_mfma(const __hip_bfloat16* __restrict__ hbT,
                   const int* __restrict__ adj,
                   const float* __restrict__ asrc, const float* __restrict__ adst,
                   const float* __restrict__ Mh,
                   float* __restrict__ out)
{
    __shared__ __align__(16) short Ps[NHEAD][16][32];   // 4 KB, A-layout per head
    __shared__ __align__(16) short Vs[HID][32];         // 32 KB, [n][k]
    __shared__ float s_l[NHEAD][16][4];
    __shared__ float s_li[NHEAD][16];

    const int t    = threadIdx.x;
    const int w    = t >> 6;        // wave id == head
    const int lane = t & 63;
    const int i0   = blockIdx.x * 16;

    // phase-A coords: this thread owns (head=w, row=prow, k in [pkq*8, pkq*8+8))
    const int prow = lane >> 2;
    const int pkq  = lane & 3;
    const float as   = asrc[w * CNODES + i0 + prow];
    const float mrow = lrelu(as + Mh[w]);
    float lsum = 0.f;

    f32x4 acc[8];
#pragma unroll
    for (int c = 0; c < 8; c++) acc[c] = (f32x4){0.f, 0.f, 0.f, 0.f};

    const short* hbTs = (const short*)hbT;
    short* vsbase = &Vs[0][0];

    for (int j0 = 0; j0 < CNODES; j0 += 32) {
        // ---- phase A: compute P tile (w values), accumulate row-sum ----
        const int kbase = j0 + pkq * 8;
        const int4*   ap = (const int4*)(adj + (size_t)(i0 + prow) * CNODES + kbase);
        const float4* dp = (const float4*)(adst + (size_t)w * CNODES + kbase);
        int4   a0 = ap[0], a1 = ap[1];
        float4 d0 = dp[0], d1 = dp[1];
        float wv[8];
        wv[0] = a0.x ? __expf(lrelu(as + d0.x) - mrow) : 0.f;
        wv[1] = a0.y ? __expf(lrelu(as + d0.y) - mrow) : 0.f;
        wv[2] = a0.z ? __expf(lrelu(as + d0.z) - mrow) : 0.f;
        wv[3] = a0.w ? __expf(lrelu(as + d0.w) - mrow) : 0.f;
        wv[4] = a1.x ? __expf(lrelu(as + d1.x) - mrow) : 0.f;
        wv[5] = a1.y ? __expf(lrelu(as + d1.y) - mrow) : 0.f;
        wv[6] = a1.z ? __expf(lrelu(as + d1.z) - mrow) : 0.f;
        wv[7] = a1.w ? __expf(lrelu(as + d1.w) - mrow) : 0.f;
        short8 pv;
#pragma unroll
        for (int q = 0; q < 8; q++) { pv[q] = f2bf(wv[q]); lsum += wv[q]; }
        *(short8*)&Ps[w][prow][pkq * 8] = pv;

        // ---- stage V tile: Vs[n][k] <- hbT[n][j0+k], 8 x 16B per thread ----
#pragma unroll
        for (int it = 0; it < 8; it++) {
            const int u = it * 256 + t;          // 16B unit index
            const int n = u >> 2, q = u & 3;
            gl_lds16(hbTs + (size_t)n * CNODES + j0 + q * 8,
                     vsbase + (size_t)(it * 256 + w * 64) * 8);
        }
        __syncthreads();

        // ---- phase B: 8 MFMA per wave ----
        const int frow = lane & 15, fq = lane >> 4;
        short8 af = *(const short8*)&Ps[w][frow][fq * 8];
#pragma unroll
        for (int c = 0; c < 8; c++) {
            short8 bf = *(const short8*)&Vs[w * HDIM + c * 16 + frow][fq * 8];
            acc[c] = __builtin_amdgcn_mfma_f32_16x16x32_bf16(af, bf, acc[c], 0, 0, 0);
        }
        __syncthreads();
    }

    // ---- l reduction ----
    s_l[w][prow][pkq] = lsum;
    __syncthreads();
    if (pkq == 0)
        s_li[w][prow] = 1.0f / (s_l[w][prow][0] + s_l[w][prow][1] +
                                s_l[w][prow][2] + s_l[w][prow][3]);
    __syncthreads();

    // ---- epilogue: C/D layout col=lane&15, row=(lane>>4)*4+reg ----
    const int col = lane & 15, q4 = lane >> 4;
#pragma unroll
    for (int c = 0; c < 8; c++)
#pragma unroll
        for (int r = 0; r < 4; r++) {
            const int row = q4 * 4 + r;
            out[(size_t)(i0 + row) * HID + w * HDIM + c * 16 + col] = acc[c][r] * s_li[w][row];
        }
}

// ---------------------------------------------------------------------------
extern "C" void kernel_launch(void* const* d_in, const int* in_sizes, int n_in,
                              void* d_out, int out_size, void* d_ws, size_t ws_size,
                              hipStream_t stream)
{
    const float* doc_x      = (const float*)d_in[0];
    const float* label_init = (const float*)d_in[1];
    const int*   adj        = (const int*)d_in[2];
    const float* W1         = (const float*)d_in[3];
    const float* a_src1     = (const float*)d_in[4];
    const float* a_dst1     = (const float*)d_in[5];
    const float* W2         = (const float*)d_in[6];
    const float* a_src2     = (const float*)d_in[7];
    const float* a_dst2     = (const float*)d_in[8];
    const float* Wd         = (const float*)d_in[9];
    const float* bd         = (const float*)d_in[10];
    float*       out        = (float*)d_out;

    float* ws    = (float*)d_ws;
    float* doc_h = ws;                          // 1024*512
    float* buf1  = doc_h + (size_t)BDOCS * HID; // 4096*512  (hpre)
    float* buf2  = buf1 + (size_t)CNODES * HID; // 4096*512  (gat out)
    float* asrc  = buf2 + (size_t)CNODES * HID; // 4*4096
    float* adst  = asrc + NHEAD * CNODES;
    float* Mh    = adst + NHEAD * CNODES;       // 4 (pad 64)
    __hip_bfloat16* hbT = (__hip_bfloat16*)(Mh + 64);  // 512*4096 bf16

    const dim3 blk(256);

    // doc_h = relu(doc_x @ Wd + bd)
    gemm64<false, false, true>
        <<<dim3(HID / 64, BDOCS / 64), blk, 0, stream>>>(doc_x, Wd, bd, doc_h, BDOCS, HID, INDIM);

    // hpre1 = label_init @ W1  -> buf1
    gemm64<false, false, false>
        <<<dim3(HID / 64, CNODES / 64), blk, 0, stream>>>(label_init, W1, nullptr, buf1, CNODES, HID, INDIM);

    // GAT layer 1
    attn_prep<<<CNODES, 512, 0, stream>>>(buf1, a_src1, a_dst1, asrc, adst);
    adst_max<<<NHEAD, 256, 0, stream>>>(adst, Mh);
    transpose_cvt<<<dim3(CNODES / 64, HID / 64), blk, 0, stream>>>(buf1, hbT);
    attn_out_mfma<<<CNODES / 16, blk, 0, stream>>>(hbT, adj, asrc, adst, Mh, buf2);

    // hpre2 = elu(buf2) @ W2 -> buf1
    gemm64<false, true, false>
        <<<dim3(HID / 64, CNODES / 64), blk, 0, stream>>>(buf2, W2, nullptr, buf1, CNODES, HID, HID);

    // GAT layer 2
    attn_prep<<<CNODES, 512, 0, stream>>>(buf1, a_src2, a_dst2, asrc, adst);
    adst_max<<<NHEAD, 256, 0, stream>>>(adst, Mh);
    transpose_cvt<<<dim3(CNODES / 64, HID / 64), blk, 0, stream>>>(buf1, hbT);
    attn_out_mfma<<<CNODES / 16, blk, 0, stream>>>(hbT, adj, asrc, adst, Mh, buf2);

    // logits = doc_h @ label_h^T -> out
    gemm64<true, false, false>
        <<<dim3(CNODES / 64, BDOCS / 64), blk, 0, stream>>>(doc_h, buf2, nullptr, out, BDOCS, CNODES, HID);
}

// Round 4
// 511.592 us; speedup vs baseline: 3.1781x; 1.4680x over previous
//
#include <hip/hip_runtime.h>
#include <hip/hip_bf16.h>
#include <math.h>

// Shapes are fixed by the problem instance.
#define BDOCS   1024
#define CNODES  4096
#define INDIM   768
#define HID     512
#define NHEAD   4
#define HDIM    128
#define NEG_SLOPE 0.2f

typedef __attribute__((ext_vector_type(8))) short short8;   // 8 bf16 (4 VGPRs)
typedef __attribute__((ext_vector_type(4))) float f32x4;    // MFMA C/D

__device__ __forceinline__ float lrelu(float x) { return x > 0.f ? x : NEG_SLOPE * x; }

// float -> bf16 bits, round-to-nearest-even
__device__ __forceinline__ short f2bf(float f) {
    union { float f; unsigned u; } v; v.f = f;
    unsigned r = (v.u + 0x7fff + ((v.u >> 16) & 1)) >> 16;
    return (short)r;
}
__device__ __forceinline__ float bf2f(short s) {
    union { float f; unsigned u; } v; v.u = ((unsigned)(unsigned short)s) << 16;
    return v.f;
}

// ---------------------------------------------------------------------------
// Tiled GEMM: C[M,N] = A[M,K] @ B[K,N]  (or A @ B^T when BT, B is [N,K])
// 64x64 tile, 256 threads, 4x4 microtile, fp32 accumulate.
// ---------------------------------------------------------------------------
template <bool BT, bool ELUA, bool BIASRELU>
__global__ __launch_bounds__(256)
void gemm64(const float* __restrict__ A, const float* __restrict__ B,
            const float* __restrict__ bias,
            float* __restrict__ Cmat, int M, int N, int K)
{
    __shared__ __align__(16) float As[16][68];
    __shared__ __align__(16) float Bs[16][68];

    const int t  = threadIdx.x;
    const int m0 = blockIdx.y * 64;
    const int n0 = blockIdx.x * 64;
    const int ty = t >> 4, tx = t & 15;

    float acc[4][4] = {};

    const int am  = t >> 2;
    const int ak0 = (t & 3) * 4;

    for (int k0 = 0; k0 < K; k0 += 16) {
        {
            const float* ap = A + (size_t)(m0 + am) * K + k0 + ak0;
#pragma unroll
            for (int q = 0; q < 4; q++) {
                float v = ap[q];
                if (ELUA) v = v > 0.f ? v : (__expf(v) - 1.f);
                As[ak0 + q][am] = v;
            }
        }
        if (!BT) {
            const int kr = t >> 4, c = (t & 15) * 4;
            const float* bp = B + (size_t)(k0 + kr) * N + n0 + c;
#pragma unroll
            for (int q = 0; q < 4; q++) Bs[kr][c + q] = bp[q];
        } else {
            const int n = t >> 2, kk0 = (t & 3) * 4;
            const float* bp = B + (size_t)(n0 + n) * K + k0 + kk0;
#pragma unroll
            for (int q = 0; q < 4; q++) Bs[kk0 + q][n] = bp[q];
        }
        __syncthreads();

#pragma unroll
        for (int kk = 0; kk < 16; kk++) {
            float4 a4 = *(const float4*)&As[kk][ty * 4];
            float4 b4 = *(const float4*)&Bs[kk][tx * 4];
            float av[4] = {a4.x, a4.y, a4.z, a4.w};
            float bv[4] = {b4.x, b4.y, b4.z, b4.w};
#pragma unroll
            for (int i2 = 0; i2 < 4; i2++)
#pragma unroll
                for (int j2 = 0; j2 < 4; j2++)
                    acc[i2][j2] += av[i2] * bv[j2];
        }
        __syncthreads();
    }

#pragma unroll
    for (int i2 = 0; i2 < 4; i2++) {
        const int m = m0 + ty * 4 + i2;
#pragma unroll
        for (int j2 = 0; j2 < 4; j2++) {
            const int n = n0 + tx * 4 + j2;
            float v = acc[i2][j2];
            if (BIASRELU) { v += bias[n]; v = fmaxf(v, 0.f); }
            Cmat[(size_t)m * N + n] = v;
        }
    }
}

// ---------------------------------------------------------------------------
// adjb64[i][jw] = bitmask of adj[i][jw*64 .. jw*64+63]
// ---------------------------------------------------------------------------
__global__ __launch_bounds__(256)
void pack_adj(const int* __restrict__ adj, unsigned long long* __restrict__ adjb64)
{
    const int t    = threadIdx.x;
    const int gw   = blockIdx.x * 4 + (t >> 6);
    const int lane = t & 63;
    const int i  = gw >> 6;
    const int j0 = (gw & 63) * 64;
    const int a  = adj[(size_t)i * CNODES + j0 + lane];
    const unsigned long long m = __ballot(a != 0);
    if (lane == 0) adjb64[(size_t)i * 64 + (j0 >> 6)] = m;
}

// ---------------------------------------------------------------------------
// asrc[h,i] = sum_d hpre[i, h*128+d] * a_src[h,d]   (same for adst)
// ---------------------------------------------------------------------------
__global__ __launch_bounds__(512)
void attn_prep(const float* __restrict__ hpre,
               const float* __restrict__ a_src,
               const float* __restrict__ a_dst,
               float* __restrict__ asrc, float* __restrict__ adst)
{
    const int i = blockIdx.x;
    const int t = threadIdx.x;  // 512 = H*D
    __shared__ float s1[512], s2[512];
    const float hv = hpre[(size_t)i * HID + t];
    s1[t] = hv * a_src[t];
    s2[t] = hv * a_dst[t];
    __syncthreads();
    for (int s = 64; s >= 1; s >>= 1) {
        if ((t & 127) < s) { s1[t] += s1[t + s]; s2[t] += s2[t + s]; }
        __syncthreads();
    }
    if ((t & 127) == 0) {
        const int h = t >> 7;
        asrc[h * CNODES + i] = s1[t];
        adst[h * CNODES + i] = s2[t];
    }
}

// ---------------------------------------------------------------------------
// Mh[h] = max_j adst[h][j]  (unmasked upper bound — softmax shift-invariant)
// ---------------------------------------------------------------------------
__global__ __launch_bounds__(256)
void adst_max(const float* __restrict__ adst, float* __restrict__ Mh)
{
    const int h = blockIdx.x, t = threadIdx.x;
    __shared__ float red[256];
    float m = -1e30f;
    for (int j = t; j < CNODES; j += 256) m = fmaxf(m, adst[h * CNODES + j]);
    red[t] = m; __syncthreads();
    for (int s = 128; s >= 1; s >>= 1) {
        if (t < s) red[t] = fmaxf(red[t], red[t + s]);
        __syncthreads();
    }
    if (t == 0) Mh[h] = red[0];
}

// ---------------------------------------------------------------------------
// hbTf: V = hpre cast to bf16, pre-swizzled into MFMA B-fragment order:
// hbTf[nb][jc][lane][jr] = bf16(hpre[jc*32 + (lane>>4)*8 + jr][nb*16 + (lane&15)])
// (nb: 16-col block 0..31, jc: 32-row chunk 0..127, lane 0..63, jr 0..7)
// ---------------------------------------------------------------------------
__global__ __launch_bounds__(256)
void transpose_frag(const float* __restrict__ hpre, short* __restrict__ hbTf)
{
    __shared__ float tile[32][129];
    const int jc = blockIdx.x;       // 0..127
    const int nq = blockIdx.y;       // 0..3  (128-col group)
    const int t  = threadIdx.x;
#pragma unroll
    for (int k = 0; k < 16; k++) {
        const int e = k * 256 + t;
        const int j = e >> 7, n = e & 127;
        tile[j][n] = hpre[(size_t)(jc * 32 + j) * HID + nq * 128 + n];
    }
    __syncthreads();
#pragma unroll
    for (int s = 0; s < 2; s++) {
        const int item = s * 256 + t;
        const int nbl = item >> 6, lane = item & 63;
        const int nr = lane & 15, kq = lane >> 4;
        short8 v;
#pragma unroll
        for (int jr = 0; jr < 8; jr++)
            v[jr] = f2bf(tile[kq * 8 + jr][nbl * 16 + nr]);
        *(short8*)&hbTf[(((size_t)(nq * 8 + nbl) * 128 + jc) * 64 + lane) * 8] = v;
    }
}

// ---------------------------------------------------------------------------
// attn_pv: partial[ks][i][n] = sum_{j in slice ks} w_ij * V[j][n], plus row
// sums lpart. Barrier-free: A-frags computed in registers, B-frags loaded
// directly from pre-swizzled hbTf. Block = 4 waves (wave = head), i-tile 32.
// ---------------------------------------------------------------------------
__global__ __launch_bounds__(256, 3)
void attn_pv(const short* __restrict__ hbTf,
             const unsigned int* __restrict__ adjb,
             const float* __restrict__ asrc, const float* __restrict__ adst,
             const float* __restrict__ Mh,
             float* __restrict__ part, float* __restrict__ lpart,
             int jper)
{
    const int t    = threadIdx.x;
    const int w    = t >> 6;        // head
    const int lane = t & 63;
    const int m    = lane & 15;
    const int kq   = lane >> 4;
    const int i0   = blockIdx.x * 32;
    const int ks   = blockIdx.y;
    const int js   = ks * jper;

    const float as0 = asrc[w * CNODES + i0 + m];
    const float as1 = asrc[w * CNODES + i0 + 16 + m];
    const float mh  = Mh[w];
    const float mr0 = lrelu(as0 + mh);
    const float mr1 = lrelu(as1 + mh);
    float ls0 = 0.f, ls1 = 0.f;

    f32x4 acc[2][8];
#pragma unroll
    for (int f = 0; f < 2; f++)
#pragma unroll
        for (int c = 0; c < 8; c++) acc[f][c] = (f32x4){0.f, 0.f, 0.f, 0.f};

    const unsigned int* ar0 = adjb + (size_t)(i0 + m) * 128 + (js >> 5);
    const unsigned int* ar1 = adjb + (size_t)(i0 + 16 + m) * 128 + (js >> 5);
    const int nchunks = jper >> 5;

    for (int ch = 0; ch < nchunks; ch++) {
        const int j0 = js + ch * 32;
        const unsigned int aw0 = ar0[ch] >> (kq * 8);
        const unsigned int aw1 = ar1[ch] >> (kq * 8);
        const float4* dp = (const float4*)(adst + (size_t)w * CNODES + j0 + kq * 8);
        const float4 d0 = dp[0], d1 = dp[1];

        // B fragments, direct from swizzled global (L2-resident)
        short8 bf[8];
        const short* bbase = hbTf + (((size_t)(w * 8) * 128 + (j0 >> 5)) * 64 + lane) * 8;
#pragma unroll
        for (int c = 0; c < 8; c++)
            bf[c] = *(const short8*)(bbase + (size_t)c * 128 * 64 * 8);

        // A fragments: P computed straight into register layout
        const float dv[8] = {d0.x, d0.y, d0.z, d0.w, d1.x, d1.y, d1.z, d1.w};
        short8 a0, a1;
#pragma unroll
        for (int q = 0; q < 8; q++) {
            const unsigned b0 = (aw0 >> q) & 1u, b1 = (aw1 >> q) & 1u;
            float w0 = b0 ? __expf(lrelu(as0 + dv[q]) - mr0) : 0.f;
            float w1 = b1 ? __expf(lrelu(as1 + dv[q]) - mr1) : 0.f;
            short r0 = f2bf(w0), r1 = f2bf(w1);
            a0[q] = r0; a1[q] = r1;
            ls0 += bf2f(r0); ls1 += bf2f(r1);
        }

#pragma unroll
        for (int c = 0; c < 8; c++) {
            acc[0][c] = __builtin_amdgcn_mfma_f32_16x16x32_bf16(a0, bf[c], acc[0][c], 0, 0, 0);
            acc[1][c] = __builtin_amdgcn_mfma_f32_16x16x32_bf16(a1, bf[c], acc[1][c], 0, 0, 0);
        }
    }

    // row-sum reduce across the 4 kq lanes holding each row
    ls0 += __shfl_xor(ls0, 16); ls0 += __shfl_xor(ls0, 32);
    ls1 += __shfl_xor(ls1, 16); ls1 += __shfl_xor(ls1, 32);
    if (lane < 16) {
        lpart[((size_t)ks * NHEAD + w) * CNODES + i0 + m]      = ls0;
        lpart[((size_t)ks * NHEAD + w) * CNODES + i0 + 16 + m] = ls1;
    }

    // epilogue: C/D layout col=lane&15, row=(lane>>4)*4+r
    float* pbase = part + (size_t)ks * CNODES * HID;
    const int col = lane & 15, q4 = lane >> 4;
#pragma unroll
    for (int f = 0; f < 2; f++)
#pragma unroll
        for (int c = 0; c < 8; c++)
#pragma unroll
            for (int r = 0; r < 4; r++) {
                const int row = i0 + f * 16 + q4 * 4 + r;
                pbase[(size_t)row * HID + w * HDIM + c * 16 + col] = acc[f][c][r];
            }
}

// ---------------------------------------------------------------------------
// outbuf[i][n] = (sum_s part[s][i][n]) / (sum_s lpart[s][h(n)][i])
// ---------------------------------------------------------------------------
__global__ __launch_bounds__(256)
void reduce_norm(const float* __restrict__ part, const float* __restrict__ lpart,
                 float* __restrict__ outbuf, int KS)
{
    const int idx = blockIdx.x * 256 + threadIdx.x;
    const int i = idx >> 9, n = idx & 511;
    const int h = n >> 7;
    float l = 0.f, v = 0.f;
    for (int s = 0; s < KS; s++) {
        l += lpart[((size_t)s * NHEAD + h) * CNODES + i];
        v += part[(size_t)s * CNODES * HID + idx];
    }
    outbuf[idx] = v / l;
}

// ---------------------------------------------------------------------------
extern "C" void kernel_launch(void* const* d_in, const int* in_sizes, int n_in,
                              void* d_out, int out_size, void* d_ws, size_t ws_size,
                              hipStream_t stream)
{
    const float* doc_x      = (const float*)d_in[0];
    const float* label_init = (const float*)d_in[1];
    const int*   adj        = (const int*)d_in[2];
    const float* W1         = (const float*)d_in[3];
    const float* a_src1     = (const float*)d_in[4];
    const float* a_dst1     = (const float*)d_in[5];
    const float* W2         = (const float*)d_in[6];
    const float* a_src2     = (const float*)d_in[7];
    const float* a_dst2     = (const float*)d_in[8];
    const float* Wd         = (const float*)d_in[9];
    const float* bd         = (const float*)d_in[10];
    float*       out        = (float*)d_out;

    float* ws = (float*)d_ws;
    size_t fo = 0;
    float* doc_h = ws + fo; fo += (size_t)BDOCS * HID;
    float* buf1  = ws + fo; fo += (size_t)CNODES * HID;
    float* buf2  = ws + fo; fo += (size_t)CNODES * HID;
    float* asrc  = ws + fo; fo += NHEAD * CNODES;
    float* adst  = ws + fo; fo += NHEAD * CNODES;
    float* Mh    = ws + fo; fo += 64;
    float* lpart = ws + fo; fo += (size_t)8 * NHEAD * CNODES;
    unsigned int* adjb = (unsigned int*)(ws + fo); fo += (size_t)CNODES * 128;   // 2 MB
    short* hbTf  = (short*)(ws + fo); fo += (size_t)CNODES * HID / 2;            // 4 MB
    float* part  = ws + fo;

    // pick largest power-of-2 K-split whose partials fit in the workspace
    int KS = 8;
    const size_t slice_bytes = (size_t)CNODES * HID * 4;
    while (KS > 1 && fo * 4 + (size_t)KS * slice_bytes > ws_size) KS >>= 1;
    const int jper = CNODES / KS;

    const dim3 blk(256);

    // adj bitmask (shared by both layers)
    pack_adj<<<CNODES * CNODES / 64 / 4, blk, 0, stream>>>(adj, (unsigned long long*)adjb);

    // doc_h = relu(doc_x @ Wd + bd)
    gemm64<false, false, true>
        <<<dim3(HID / 64, BDOCS / 64), blk, 0, stream>>>(doc_x, Wd, bd, doc_h, BDOCS, HID, INDIM);

    // hpre1 = label_init @ W1  -> buf1
    gemm64<false, false, false>
        <<<dim3(HID / 64, CNODES / 64), blk, 0, stream>>>(label_init, W1, nullptr, buf1, CNODES, HID, INDIM);

    // GAT layer 1
    attn_prep<<<CNODES, 512, 0, stream>>>(buf1, a_src1, a_dst1, asrc, adst);
    adst_max<<<NHEAD, 256, 0, stream>>>(adst, Mh);
    transpose_frag<<<dim3(128, 4), blk, 0, stream>>>(buf1, hbTf);
    attn_pv<<<dim3(CNODES / 32, KS), blk, 0, stream>>>(hbTf, adjb, asrc, adst, Mh, part, lpart, jper);
    reduce_norm<<<CNODES * HID / 256, blk, 0, stream>>>(part, lpart, buf2, KS);

    // hpre2 = elu(buf2) @ W2 -> buf1
    gemm64<false, true, false>
        <<<dim3(HID / 64, CNODES / 64), blk, 0, stream>>>(buf2, W2, nullptr, buf1, CNODES, HID, HID);

    // GAT layer 2
    attn_prep<<<CNODES, 512, 0, stream>>>(buf1, a_src2, a_dst2, asrc, adst);
    adst_max<<<NHEAD, 256, 0, stream>>>(adst, Mh);
    transpose_frag<<<dim3(128, 4), blk, 0, stream>>>(buf1, hbTf);
    attn_pv<<<dim3(CNODES / 32, KS), blk, 0, stream>>>(hbTf, adjb, asrc, adst, Mh, part, lpart, jper);
    reduce_norm<<<CNODES * HID / 256, blk, 0, stream>>>(part, lpart, buf2, KS);

    // logits = doc_h @ label_h^T -> out
    gemm64<true, false, false>
        <<<dim3(CNODES / 64, BDOCS / 64), blk, 0, stream>>>(doc_h, buf2, nullptr, out, BDOCS, CNODES, HID);
}

// Round 5
// 370.963 us; speedup vs baseline: 4.3829x; 1.3791x over previous
//
#include <hip/hip_runtime.h>
#include <hip/hip_bf16.h>
#include <math.h>

// Shapes are fixed by the problem instance.
#define BDOCS   1024
#define CNODES  4096
#define INDIM   768
#define HID     512
#define NHEAD   4
#define HDIM    128
#define NEG_SLOPE 0.2f

typedef __attribute__((ext_vector_type(8))) short short8;   // 8 bf16 (4 VGPRs)
typedef __attribute__((ext_vector_type(4))) float f32x4;    // MFMA C/D

__device__ __forceinline__ float lrelu(float x) { return x > 0.f ? x : NEG_SLOPE * x; }

// float -> bf16 bits, round-to-nearest-even
__device__ __forceinline__ short f2bf(float f) {
    union { float f; unsigned u; } v; v.f = f;
    unsigned r = (v.u + 0x7fff + ((v.u >> 16) & 1)) >> 16;
    return (short)r;
}
__device__ __forceinline__ float bf2f(short s) {
    union { float f; unsigned u; } v; v.u = ((unsigned)(unsigned short)s) << 16;
    return v.f;
}

// ---------------------------------------------------------------------------
// adjb64[i][jw] = bitmask of adj[i][jw*64 .. jw*64+63]
// ---------------------------------------------------------------------------
__global__ __launch_bounds__(256)
void pack_adj(const int* __restrict__ adj, unsigned long long* __restrict__ adjb64)
{
    const int t    = threadIdx.x;
    const int gw   = blockIdx.x * 4 + (t >> 6);
    const int lane = t & 63;
    const int i  = gw >> 6;
    const int j0 = (gw & 63) * 64;
    const int a  = adj[(size_t)i * CNODES + j0 + lane];
    const unsigned long long m = __ballot(a != 0);
    if (lane == 0) adjb64[(size_t)i * 64 + (j0 >> 6)] = m;
}

// ---------------------------------------------------------------------------
// asrc[h,i] = sum_d hpre[i, h*128+d] * a_src[h,d]   (same for adst)
// ---------------------------------------------------------------------------
__global__ __launch_bounds__(512)
void attn_prep(const float* __restrict__ hpre,
               const float* __restrict__ a_src,
               const float* __restrict__ a_dst,
               float* __restrict__ asrc, float* __restrict__ adst)
{
    const int i = blockIdx.x;
    const int t = threadIdx.x;  // 512 = H*D
    __shared__ float s1[512], s2[512];
    const float hv = hpre[(size_t)i * HID + t];
    s1[t] = hv * a_src[t];
    s2[t] = hv * a_dst[t];
    __syncthreads();
    for (int s = 64; s >= 1; s >>= 1) {
        if ((t & 127) < s) { s1[t] += s1[t + s]; s2[t] += s2[t + s]; }
        __syncthreads();
    }
    if ((t & 127) == 0) {
        const int h = t >> 7;
        asrc[h * CNODES + i] = s1[t];
        adst[h * CNODES + i] = s2[t];
    }
}

// ---------------------------------------------------------------------------
// Mh[h] = max_j adst[h][j]  (unmasked upper bound — softmax shift-invariant)
// ---------------------------------------------------------------------------
__global__ __launch_bounds__(256)
void adst_max(const float* __restrict__ adst, float* __restrict__ Mh)
{
    const int h = blockIdx.x, t = threadIdx.x;
    __shared__ float red[256];
    float m = -1e30f;
    for (int j = t; j < CNODES; j += 256) m = fmaxf(m, adst[h * CNODES + j]);
    red[t] = m; __syncthreads();
    for (int s = 128; s >= 1; s >>= 1) {
        if (t < s) red[t] = fmaxf(red[t], red[t + s]);
        __syncthreads();
    }
    if (t == 0) Mh[h] = red[0];
}

// ---------------------------------------------------------------------------
// frag_T: src fp32 [K][N] row-major -> dst bf16 B-fragment order:
// dst[((nb*(K/32) + kc)*64 + lane)*8 + j] = bf16(src[kc*32+(lane>>4)*8+j][nb*16+(lane&15)])
// grid (K/32, N/128). Also produces hbTf from hpre (K=CNODES, N=HID).
// ---------------------------------------------------------------------------
__global__ __launch_bounds__(256)
void frag_T(const float* __restrict__ src, short* __restrict__ dst, int N, int K)
{
    __shared__ float tile[32][132];
    const int jc = blockIdx.x;   // K/32
    const int nq = blockIdx.y;   // N/128
    const int t  = threadIdx.x;
    const int KC = K >> 5;
#pragma unroll
    for (int it = 0; it < 16; it++) {
        const int e = it * 256 + t;
        const int j = e >> 7, n = e & 127;
        tile[j][n] = src[(size_t)(jc * 32 + j) * N + nq * 128 + n];
    }
    __syncthreads();
#pragma unroll
    for (int s = 0; s < 2; s++) {
        const int item = s * 256 + t;
        const int nbl = item >> 6, lane = item & 63;
        const int nr = lane & 15, kq = lane >> 4;
        short8 v;
#pragma unroll
        for (int jr = 0; jr < 8; jr++)
            v[jr] = f2bf(tile[kq * 8 + jr][nbl * 16 + nr]);
        *(short8*)&dst[((size_t)((nq * 8 + nbl) * KC + jc) * 64 + lane) * 8] = v;
    }
}

// ---------------------------------------------------------------------------
// frag_A: src fp32 [R][C] row-major -> dst bf16 A-fragment order (same index
// math as B-frags): dst[((rb*(C/32)+kc)*64+lane)*8+j] =
//   bf16(src[rb*16+(lane&15)][kc*32+(lane>>4)*8+j]).   grid (R/16, C/128).
// ---------------------------------------------------------------------------
template <bool ELU>
__global__ __launch_bounds__(256)
void frag_A(const float* __restrict__ src, short* __restrict__ dst, int C)
{
    __shared__ float tile[16][132];
    const int rb = blockIdx.x, cq = blockIdx.y;
    const int t  = threadIdx.x;
    const int KC = C >> 5;
#pragma unroll
    for (int it = 0; it < 8; it++) {
        const int e = it * 256 + t;
        const int r = e >> 7, c = e & 127;
        float v = src[(size_t)(rb * 16 + r) * C + cq * 128 + c];
        if (ELU) v = v > 0.f ? v : (__expf(v) - 1.f);
        tile[r][c] = v;
    }
    __syncthreads();
    const int kcl = t >> 6, lane = t & 63;
    const int m = lane & 15, kq = lane >> 4;
    short8 v8;
#pragma unroll
    for (int j = 0; j < 8; j++) v8[j] = f2bf(tile[m][kcl * 32 + kq * 8 + j]);
    *(short8*)&dst[((size_t)(rb * KC + cq * 4 + kcl) * 64 + lane) * 8] = v8;
}

// ---------------------------------------------------------------------------
// gemm_frag: C[M][N] = A @ B^T from pre-swizzled bf16 fragments. 1-wave
// blocks, barrier-free, no LDS. m-tile 32 (2 A-frags), n-tile 128 (8 B-frags).
// grid (M/32, N/128). KC = K/32 compile-time.
// ---------------------------------------------------------------------------
template <int KC, bool BIASRELU>
__global__ __launch_bounds__(64, 3)
void gemm_frag(const short* __restrict__ Af, const short* __restrict__ Bf,
               const float* __restrict__ bias, float* __restrict__ Cmat, int N)
{
    const int lane = threadIdx.x;
    const int mb0  = blockIdx.x * 2;
    const int nq   = blockIdx.y;

    f32x4 acc[2][8];
#pragma unroll
    for (int f = 0; f < 2; f++)
#pragma unroll
        for (int c = 0; c < 8; c++) acc[f][c] = (f32x4){0.f, 0.f, 0.f, 0.f};

    const short* ap0 = Af + (size_t)mb0 * KC * 512 + lane * 8;
    const short* ap1 = ap0 + (size_t)KC * 512;
    const short* bp  = Bf + (size_t)(nq * 8) * KC * 512 + lane * 8;

#pragma unroll 2
    for (int kc = 0; kc < KC; kc++) {
        short8 a0 = *(const short8*)(ap0 + (size_t)kc * 512);
        short8 a1 = *(const short8*)(ap1 + (size_t)kc * 512);
        short8 bf[8];
#pragma unroll
        for (int c = 0; c < 8; c++)
            bf[c] = *(const short8*)(bp + ((size_t)c * KC + kc) * 512);
#pragma unroll
        for (int c = 0; c < 8; c++) {
            acc[0][c] = __builtin_amdgcn_mfma_f32_16x16x32_bf16(a0, bf[c], acc[0][c], 0, 0, 0);
            acc[1][c] = __builtin_amdgcn_mfma_f32_16x16x32_bf16(a1, bf[c], acc[1][c], 0, 0, 0);
        }
    }

    const int col = lane & 15, q4 = lane >> 4;
#pragma unroll
    for (int f = 0; f < 2; f++)
#pragma unroll
        for (int c = 0; c < 8; c++)
#pragma unroll
            for (int r = 0; r < 4; r++) {
                const int row = (mb0 + f) * 16 + q4 * 4 + r;
                const int n   = nq * 128 + c * 16 + col;
                float v = acc[f][c][r];
                if (BIASRELU) v = fmaxf(v + bias[n], 0.f);
                Cmat[(size_t)row * N + n] = v;
            }
}

// ---------------------------------------------------------------------------
// attn_pv: partial[ks][i][n] = sum_{j in slice ks} w_ij * V[j][n], plus row
// sums lpart. Barrier-free: A-frags computed in registers, B-frags loaded
// directly from pre-swizzled hbTf. Block = 4 waves (wave = head), i-tile 32.
// ---------------------------------------------------------------------------
__global__ __launch_bounds__(256, 3)
void attn_pv(const short* __restrict__ hbTf,
             const unsigned int* __restrict__ adjb,
             const float* __restrict__ asrc, const float* __restrict__ adst,
             const float* __restrict__ Mh,
             float* __restrict__ part, float* __restrict__ lpart,
             int jper)
{
    const int t    = threadIdx.x;
    const int w    = t >> 6;        // head
    const int lane = t & 63;
    const int m    = lane & 15;
    const int kq   = lane >> 4;
    const int i0   = blockIdx.x * 32;
    const int ks   = blockIdx.y;
    const int js   = ks * jper;

    const float as0 = asrc[w * CNODES + i0 + m];
    const float as1 = asrc[w * CNODES + i0 + 16 + m];
    const float mh  = Mh[w];
    const float mr0 = lrelu(as0 + mh);
    const float mr1 = lrelu(as1 + mh);
    float ls0 = 0.f, ls1 = 0.f;

    f32x4 acc[2][8];
#pragma unroll
    for (int f = 0; f < 2; f++)
#pragma unroll
        for (int c = 0; c < 8; c++) acc[f][c] = (f32x4){0.f, 0.f, 0.f, 0.f};

    const unsigned int* ar0 = adjb + (size_t)(i0 + m) * 128 + (js >> 5);
    const unsigned int* ar1 = adjb + (size_t)(i0 + 16 + m) * 128 + (js >> 5);
    const int nchunks = jper >> 5;

    for (int ch = 0; ch < nchunks; ch++) {
        const int j0 = js + ch * 32;
        const unsigned int aw0 = ar0[ch] >> (kq * 8);
        const unsigned int aw1 = ar1[ch] >> (kq * 8);
        const float4* dp = (const float4*)(adst + (size_t)w * CNODES + j0 + kq * 8);
        const float4 d0 = dp[0], d1 = dp[1];

        // B fragments, direct from swizzled global (L2-resident)
        short8 bf[8];
        const short* bbase = hbTf + (((size_t)(w * 8) * 128 + (j0 >> 5)) * 64 + lane) * 8;
#pragma unroll
        for (int c = 0; c < 8; c++)
            bf[c] = *(const short8*)(bbase + (size_t)c * 128 * 64 * 8);

        // A fragments: P computed straight into register layout
        const float dv[8] = {d0.x, d0.y, d0.z, d0.w, d1.x, d1.y, d1.z, d1.w};
        short8 a0, a1;
#pragma unroll
        for (int q = 0; q < 8; q++) {
            const unsigned b0 = (aw0 >> q) & 1u, b1 = (aw1 >> q) & 1u;
            float w0 = b0 ? __expf(lrelu(as0 + dv[q]) - mr0) : 0.f;
            float w1 = b1 ? __expf(lrelu(as1 + dv[q]) - mr1) : 0.f;
            short r0 = f2bf(w0), r1 = f2bf(w1);
            a0[q] = r0; a1[q] = r1;
            ls0 += bf2f(r0); ls1 += bf2f(r1);
        }

#pragma unroll
        for (int c = 0; c < 8; c++) {
            acc[0][c] = __builtin_amdgcn_mfma_f32_16x16x32_bf16(a0, bf[c], acc[0][c], 0, 0, 0);
            acc[1][c] = __builtin_amdgcn_mfma_f32_16x16x32_bf16(a1, bf[c], acc[1][c], 0, 0, 0);
        }
    }

    // row-sum reduce across the 4 kq lanes holding each row
    ls0 += __shfl_xor(ls0, 16); ls0 += __shfl_xor(ls0, 32);
    ls1 += __shfl_xor(ls1, 16); ls1 += __shfl_xor(ls1, 32);
    if (lane < 16) {
        lpart[((size_t)ks * NHEAD + w) * CNODES + i0 + m]      = ls0;
        lpart[((size_t)ks * NHEAD + w) * CNODES + i0 + 16 + m] = ls1;
    }

    // epilogue: C/D layout col=lane&15, row=(lane>>4)*4+r
    float* pbase = part + (size_t)ks * CNODES * HID;
    const int col = lane & 15, q4 = lane >> 4;
#pragma unroll
    for (int f = 0; f < 2; f++)
#pragma unroll
        for (int c = 0; c < 8; c++)
#pragma unroll
            for (int r = 0; r < 4; r++) {
                const int row = i0 + f * 16 + q4 * 4 + r;
                pbase[(size_t)row * HID + w * HDIM + c * 16 + col] = acc[f][c][r];
            }
}

// ---------------------------------------------------------------------------
// outbuf[i][n] = (sum_s part[s][i][n]) / (sum_s lpart[s][h(n)][i])
// ---------------------------------------------------------------------------
__global__ __launch_bounds__(256)
void reduce_norm(const float* __restrict__ part, const float* __restrict__ lpart,
                 float* __restrict__ outbuf, int KS)
{
    const int idx = blockIdx.x * 256 + threadIdx.x;
    const int i = idx >> 9, n = idx & 511;
    const int h = n >> 7;
    float l = 0.f, v = 0.f;
    for (int s = 0; s < KS; s++) {
        l += lpart[((size_t)s * NHEAD + h) * CNODES + i];
        v += part[(size_t)s * CNODES * HID + idx];
    }
    outbuf[idx] = v / l;
}

// ---------------------------------------------------------------------------
extern "C" void kernel_launch(void* const* d_in, const int* in_sizes, int n_in,
                              void* d_out, int out_size, void* d_ws, size_t ws_size,
                              hipStream_t stream)
{
    const float* doc_x      = (const float*)d_in[0];
    const float* label_init = (const float*)d_in[1];
    const int*   adj        = (const int*)d_in[2];
    const float* W1         = (const float*)d_in[3];
    const float* a_src1     = (const float*)d_in[4];
    const float* a_dst1     = (const float*)d_in[5];
    const float* W2         = (const float*)d_in[6];
    const float* a_src2     = (const float*)d_in[7];
    const float* a_dst2     = (const float*)d_in[8];
    const float* Wd         = (const float*)d_in[9];
    const float* bd         = (const float*)d_in[10];
    float*       out        = (float*)d_out;

    char* wsb = (char*)d_ws;
    size_t off = 0;
    auto alloc = [&](size_t bytes) -> char* {
        char* p = wsb + off;
        off = (off + bytes + 255) & ~(size_t)255;
        return p;
    };

    float* doc_h = (float*)alloc((size_t)BDOCS * HID * 4);
    float* buf1  = (float*)alloc((size_t)CNODES * HID * 4);
    float* buf2  = (float*)alloc((size_t)CNODES * HID * 4);
    float* asrc  = (float*)alloc(NHEAD * CNODES * 4);
    float* adst  = (float*)alloc(NHEAD * CNODES * 4);
    float* Mh    = (float*)alloc(256);
    float* lpart = (float*)alloc((size_t)4 * NHEAD * CNODES * 4);
    unsigned int* adjb = (unsigned int*)alloc((size_t)CNODES * 128 * 4);        // 2 MB
    short* hbTf  = (short*)alloc((size_t)CNODES * HID * 2);                     // 4 MB
    short* Wdf   = (short*)alloc((size_t)INDIM * HID * 2);
    short* W1f   = (short*)alloc((size_t)INDIM * HID * 2);
    short* W2f   = (short*)alloc((size_t)HID * HID * 2);
    short* dxf   = (short*)alloc((size_t)BDOCS * INDIM * 2);
    // aliased region: Af_li (6 MB, dead after hpre1) overlaps Af2 (4 MB) and
    // lhf's first 2 MB (both written long after hpre1). dhf sits past 6 MB.
    char*  reg   = alloc((size_t)9 << 20);
    short* Af_li = (short*)reg;                          // 4096x768
    short* Af2   = (short*)reg;                          // 4096x512
    short* lhf   = (short*)(reg + ((size_t)4 << 20));    // 4096x512
    short* dhf   = (short*)(reg + ((size_t)8 << 20));    // 1024x512
    float* part  = (float*)(wsb + off);

    // pick largest power-of-2 K-split whose partials fit in the workspace
    int KS = 4;
    const size_t slice_bytes = (size_t)CNODES * HID * 4;
    while (KS > 1 && off + (size_t)KS * slice_bytes > ws_size) KS >>= 1;
    const int jper = CNODES / KS;

    const dim3 blk(256);

    // one-time transforms
    pack_adj<<<CNODES * CNODES / 64 / 4, blk, 0, stream>>>(adj, (unsigned long long*)adjb);
    frag_T<<<dim3(INDIM / 32, HID / 128), blk, 0, stream>>>(Wd, Wdf, HID, INDIM);
    frag_T<<<dim3(INDIM / 32, HID / 128), blk, 0, stream>>>(W1, W1f, HID, INDIM);
    frag_T<<<dim3(HID / 32, HID / 128), blk, 0, stream>>>(W2, W2f, HID, HID);
    frag_A<false><<<dim3(BDOCS / 16, INDIM / 128), blk, 0, stream>>>(doc_x, dxf, INDIM);
    frag_A<false><<<dim3(CNODES / 16, INDIM / 128), blk, 0, stream>>>(label_init, Af_li, INDIM);

    // hpre1 = label_init @ W1 -> buf1
    gemm_frag<INDIM / 32, false><<<dim3(CNODES / 32, HID / 128), 64, 0, stream>>>(Af_li, W1f, nullptr, buf1, HID);

    // doc_h = relu(doc_x @ Wd + bd); then to A-frags for logits
    gemm_frag<INDIM / 32, true><<<dim3(BDOCS / 32, HID / 128), 64, 0, stream>>>(dxf, Wdf, bd, doc_h, HID);
    frag_A<false><<<dim3(BDOCS / 16, HID / 128), blk, 0, stream>>>(doc_h, dhf, HID);

    // GAT layer 1
    attn_prep<<<CNODES, 512, 0, stream>>>(buf1, a_src1, a_dst1, asrc, adst);
    adst_max<<<NHEAD, 256, 0, stream>>>(adst, Mh);
    frag_T<<<dim3(CNODES / 32, HID / 128), blk, 0, stream>>>(buf1, hbTf, HID, CNODES);
    attn_pv<<<dim3(CNODES / 32, KS), blk, 0, stream>>>(hbTf, adjb, asrc, adst, Mh, part, lpart, jper);
    reduce_norm<<<CNODES * HID / 256, blk, 0, stream>>>(part, lpart, buf2, KS);

    // hpre2 = elu(buf2) @ W2 -> buf1
    frag_A<true><<<dim3(CNODES / 16, HID / 128), blk, 0, stream>>>(buf2, Af2, HID);
    gemm_frag<HID / 32, false><<<dim3(CNODES / 32, HID / 128), 64, 0, stream>>>(Af2, W2f, nullptr, buf1, HID);

    // GAT layer 2
    attn_prep<<<CNODES, 512, 0, stream>>>(buf1, a_src2, a_dst2, asrc, adst);
    adst_max<<<NHEAD, 256, 0, stream>>>(adst, Mh);
    frag_T<<<dim3(CNODES / 32, HID / 128), blk, 0, stream>>>(buf1, hbTf, HID, CNODES);
    attn_pv<<<dim3(CNODES / 32, KS), blk, 0, stream>>>(hbTf, adjb, asrc, adst, Mh, part, lpart, jper);
    reduce_norm<<<CNODES * HID / 256, blk, 0, stream>>>(part, lpart, buf2, KS);

    // logits = doc_h @ label_h^T -> out
    frag_A<false><<<dim3(CNODES / 16, HID / 128), blk, 0, stream>>>(buf2, lhf, HID);
    gemm_frag<HID / 32, false><<<dim3(BDOCS / 32, CNODES / 128), 64, 0, stream>>>(dhf, lhf, nullptr, out, CNODES);
}